// Round 5
// baseline (268.509 us; speedup 1.0000x reference)
//
#include <hip/hip_runtime.h>
#include <hip/hip_bf16.h>
#include <cstddef>
#include <cstdint>

#define B_ 32
#define T_ 2048
#define D_ 512
#define U_ 512

typedef __attribute__((ext_vector_type(8))) short bf16x8;   // 8 bf16 = 4 VGPRs
typedef __attribute__((ext_vector_type(4))) float f32x4;    // MFMA 16x16 accum

__device__ __forceinline__ unsigned short f2bf(float f) {
  union { float f; unsigned u; } x; x.f = f;
  unsigned r = x.u + 0x7fffu + ((x.u >> 16) & 1u);  // RNE
  return (unsigned short)(r >> 16);
}
__device__ __forceinline__ float tanh_fast(float x) {
  float e = __expf(2.0f * x);
  return 1.0f - 2.0f * __builtin_amdgcn_rcpf(e + 1.0f);
}

#define AS1C(p) ((const __attribute__((address_space(1))) unsigned*)(p))
#define AS3(p)  ((__attribute__((address_space(3))) unsigned*)(p))

// C = sum |Vw| : tanh-bound => |score| <= C, so exp(s-C) in (0,1] -- softmax needs no
// global max pass. Computed IDENTICALLY (wave-0 only, fixed shfl order) in k2attn and
// kB_final => bit-identical C in both kernels.
__device__ __forceinline__ void wave0_sumabs_vw(const float* __restrict__ Vw,
                                                float* Cs, int tid) {
  if (tid < 64) {
    float c = 0.f;
    #pragma unroll
    for (int i = 0; i < 8; ++i) c += fabsf(Vw[tid + i * 64]);
    c += __shfl_xor(c, 1);  c += __shfl_xor(c, 2);  c += __shfl_xor(c, 4);
    c += __shfl_xor(c, 8);  c += __shfl_xor(c, 16); c += __shfl_xor(c, 32);
    if (tid == 0) *Cs = c;
  }
}

// ---------- kA: W2 pack (blocks 0..63, 4x wider than R4) + q_proj/ctx-zero (64..319) ----------
// Pack identity: W2P[p], p = ut*4096 + kg*256 + q4*64 + idx; u = ut*16 + ((idx>>2)&15),
// k = kg*32 + q4*8 + (idx&3)*2 (+1 for hi half). Block = (kg,q4) owns 8 k-rows.
__global__ void kA_prep(const float* __restrict__ W2, unsigned* __restrict__ W2P,
                        const float* __restrict__ query, const float* __restrict__ W1,
                        const float* __restrict__ W1b, const float* __restrict__ W2b,
                        float* __restrict__ qp, float* __restrict__ ctx) {
  const int tid = threadIdx.x;              // 256
  if (blockIdx.x < 64) {
    const int kg = blockIdx.x >> 2, q4 = blockIdx.x & 3;  // 8 k-rows: kg*32+q4*8 ..+7
    __shared__ unsigned short w2s[8][514];
    const float4* W2v = (const float4*)(W2 + (size_t)(kg * 32 + q4 * 8) * U_);
    #pragma unroll
    for (int i = 0; i < 4; ++i) {
      int idx4 = i * 256 + tid;             // float4 index in 8x512 slab (128 per row)
      float4 v = W2v[idx4];
      int r = idx4 >> 7, c = (idx4 & 127) * 4;
      w2s[r][c + 0] = f2bf(v.x); w2s[r][c + 1] = f2bf(v.y);
      w2s[r][c + 2] = f2bf(v.z); w2s[r][c + 3] = f2bf(v.w);
    }
    __syncthreads();
    const int idx = tid & 63;               // lr = (idx>>2)&15, j = idx&3
    const int lr = (idx >> 2) & 15, j = idx & 3;
    const int kb = j * 2;                   // local row within the 8-row slab
    #pragma unroll
    for (int r = 0; r < 8; ++r) {
      int ut = r * 4 + (tid >> 6);
      W2P[ut * 4096 + kg * 256 + q4 * 64 + idx] =
          (unsigned)w2s[kb][ut * 16 + lr] | ((unsigned)w2s[kb + 1][ut * 16 + lr] << 16);
    }
  } else {
    // qproj: 256 blocks = 32 b x 8 u-slices(64). 4-way d-split per u + LDS reduce.
    __shared__ float qs[D_];
    __shared__ float red[4][64];
    const int blk2 = blockIdx.x - 64;       // 0..255
    const int b = blk2 >> 3, us = blk2 & 7;
    const int ul = tid & 63, dq = tid >> 6; // u-local, d-quarter
    const int u = us * 64 + ul;
    qs[tid] = query[b * D_ + tid];
    qs[tid + 256] = query[b * D_ + tid + 256];
    __syncthreads();
    float a0 = 0, a1 = 0, a2 = 0, a3 = 0;
    const int d0 = dq * 128;
    for (int d = 0; d < 128; d += 4) {
      a0 += qs[d0 + d + 0] * W1[(size_t)(d0 + d + 0) * U_ + u];
      a1 += qs[d0 + d + 1] * W1[(size_t)(d0 + d + 1) * U_ + u];
      a2 += qs[d0 + d + 2] * W1[(size_t)(d0 + d + 2) * U_ + u];
      a3 += qs[d0 + d + 3] * W1[(size_t)(d0 + d + 3) * U_ + u];
    }
    red[dq][ul] = (a0 + a1) + (a2 + a3);
    __syncthreads();
    if (dq == 0) {
      float s = red[0][ul] + red[1][ul] + red[2][ul] + red[3][ul];
      qp[b * U_ + u] = s + W1b[u] + W2b[u];
    }
    if (tid < 64) ctx[blk2 * 64 + tid] = 0.0f;  // 256*64 = 16384: zero unnormalized ctx
  }
}

// ---------- k2attn v5: M=64, full U, DMA-A, FIFO-audited counted-vmcnt pipeline ----------
// 1024 blocks x 1024 thr (16 waves: h=w>>3 m-half, uw=w&7 u-group; wave = 2mi x 4ni, acc 32).
// A: fp32 eighths (16 KB) via global_load_lds DMA, ring-3 (48 KB), stage distance 2,
//    R0-verified XOR swizzle (0 conflicts): chunk q = dchunk ^ (row&15); read p0=(kq*8+lq*2)^lr.
// B: ring-3 in regs, issue B(kappa+2)/B(kappa+3) one phase ahead, pinned by sched_barrier(0)
//    (R4's ring was silently sunk to JIT by the compiler -- VGPR=64 proved it).
// FIFO audit (per phase e issues, in order: B(2e+2){4}, B(2e+3){4}, st(e+2){1}):
//    stage is NEWER than every B waited on before its deadline -> compiler B-waits
//    (vmcnt(9)) never early-drain stages; barrier-e waits vmcnt(9) (e<=5; 8 at e=6)
//    = drains exactly st(e+1). No lgkm needed in-loop (no ds_writes; DMA is vmcnt).
// Fused epilogue (R3/R4-verified): tanh+Vw reduce -> score + p=exp(s-C) -> L2-warm ctx.
__global__ __launch_bounds__(1024, 4) void k2attn(
    const float* __restrict__ values, const unsigned short* __restrict__ W2P,
    const float* __restrict__ qp, const float* __restrict__ Vw,
    float* __restrict__ score, float* __restrict__ ctxU) {
  __shared__ __align__(16) float av[3][4096];   // 3 x 16 KB fp32 A buffers (64 rows x 64 f)
  __shared__ float sred[16][32];
  __shared__ float ps2[64];
  __shared__ float pc[512];
  __shared__ float Cs;

  const int tid = threadIdx.x;              // 1024
  const int bx = blockIdx.x;                // 1024 = 32 chunks x 32 batches
  const int m0 = bx * 64;                   // 2048%64==0: never crosses batch
  const int b = m0 >> 11;
  const int l = tid & 63, w = tid >> 6;     // 16 waves
  const int lr = l & 15, lq = l >> 4;
  const int h = w >> 3, uw = w & 7;         // m-half, u-group

  // staging role: wave w stages chunk w (rows w*4..w*4+3); 1 DMA(16B)/thread/eighth
  const int row_g = w * 4 + (l >> 4);
  const int qsw = (l & 15) ^ (row_g & 15);  // swizzled source chunk (R0-verified)
  const float* vsrc = values + (size_t)(m0 + row_g) * D_ + qsw * 4;

  f32x4 acc[2][4];
  #pragma unroll
  for (int mi = 0; mi < 2; ++mi)
    #pragma unroll
    for (int ni = 0; ni < 4; ++ni) acc[mi][ni] = (f32x4){0.f, 0.f, 0.f, 0.f};

  const unsigned short* Bb = W2P + (size_t)(uw * 4) * 8192 + (size_t)l * 8;

  auto stage = [&](int s) {                 // DMA eighth s into av[s%3]
    __builtin_amdgcn_global_load_lds(AS1C(vsrc + s * 64), AS3(&av[s % 3][w * 256]), 16, 0, 0);
  };
  bf16x8 Bf[3][4];                          // B ring: kq-step kappa in Bf[kappa%3]
  auto loadB = [&](int slot, int kappa) {
    #pragma unroll
    for (int ni = 0; ni < 4; ++ni)
      Bf[slot][ni] = *(const bf16x8*)(Bb + (size_t)ni * 8192 + (size_t)kappa * 512);
  };

  wave0_sumabs_vw(Vw, &Cs, tid);            // oldest vmem (wave0 only); drained at prologue

  // prologue order matters for FIFO audit: B(0), B(1), st(0), st(1)
  loadB(0, 0);
  loadB(1, 1);
  stage(0);
  stage(1);
  __builtin_amdgcn_sched_barrier(0);
  asm volatile("s_waitcnt vmcnt(1) lgkmcnt(0)" ::: "memory");  // drain st(0) (+B0,B1,Cs)
  __builtin_amdgcn_s_barrier();
  __builtin_amdgcn_sched_barrier(0);
  const float C = Cs;

  #pragma unroll
  for (int e = 0; e < 8; ++e) {             // K = 512 = 8 eighths x (2 x K32)
    const float* buf = (const float*)av[e % 3];
    #pragma unroll
    for (int kq = 0; kq < 2; ++kq) {
      const int kappa = e * 2 + kq;
      if (kappa + 2 < 16) loadB((kappa + 2) % 3, kappa + 2);   // 1-phase lookahead
      __builtin_amdgcn_sched_barrier(0);                        // pin issue above MFMAs
      const int p0 = (kq * 8 + lq * 2) ^ lr;
      #pragma unroll
      for (int mi = 0; mi < 2; ++mi) {
        const int row = h * 32 + mi * 16 + lr;                  // row&15 == lr
        f32x4 flo = *(const f32x4*)&buf[row * 64 + (p0 << 2)];
        f32x4 fhi = *(const f32x4*)&buf[row * 64 + ((p0 ^ 1) << 2)];
        union { bf16x8 v; __hip_bfloat162 hh[4]; } A;
        A.hh[0] = __float22bfloat162_rn(make_float2(flo.x, flo.y));
        A.hh[1] = __float22bfloat162_rn(make_float2(flo.z, flo.w));
        A.hh[2] = __float22bfloat162_rn(make_float2(fhi.x, fhi.y));
        A.hh[3] = __float22bfloat162_rn(make_float2(fhi.z, fhi.w));
        __builtin_amdgcn_s_setprio(1);
        acc[mi][0] = __builtin_amdgcn_mfma_f32_16x16x32_bf16(A.v, Bf[kappa % 3][0], acc[mi][0], 0, 0, 0);
        acc[mi][1] = __builtin_amdgcn_mfma_f32_16x16x32_bf16(A.v, Bf[kappa % 3][1], acc[mi][1], 0, 0, 0);
        acc[mi][2] = __builtin_amdgcn_mfma_f32_16x16x32_bf16(A.v, Bf[kappa % 3][2], acc[mi][2], 0, 0, 0);
        acc[mi][3] = __builtin_amdgcn_mfma_f32_16x16x32_bf16(A.v, Bf[kappa % 3][3], acc[mi][3], 0, 0, 0);
        __builtin_amdgcn_s_setprio(0);
      }
    }
    if (e + 2 < 8) stage(e + 2);            // newest vmem of the phase (FIFO audit)
    __builtin_amdgcn_sched_barrier(0);
    if (e < 7) {                            // barrier-e: drain exactly st(e+1)
      if (e == 6) asm volatile("s_waitcnt vmcnt(8)" ::: "memory");
      else        asm volatile("s_waitcnt vmcnt(9)" ::: "memory");
      __builtin_amdgcn_s_barrier();
      __builtin_amdgcn_sched_barrier(0);
    }
  }

  // ---- epilogue 1: tanh + Vw-weighted reduce over u ----
  float sacc[2][4];
  #pragma unroll
  for (int mi = 0; mi < 2; ++mi)
    #pragma unroll
    for (int r = 0; r < 4; ++r) sacc[mi][r] = 0.0f;
  #pragma unroll
  for (int ni = 0; ni < 4; ++ni) {
    int u = (uw * 4 + ni) * 16 + lr;
    float qpv = qp[b * U_ + u], vv = Vw[u];
    #pragma unroll
    for (int mi = 0; mi < 2; ++mi)
      #pragma unroll
      for (int r = 0; r < 4; ++r)
        sacc[mi][r] += tanh_fast(acc[mi][ni][r] + qpv) * vv;
  }
  #pragma unroll
  for (int mi = 0; mi < 2; ++mi)
    #pragma unroll
    for (int r = 0; r < 4; ++r) {
      float v = sacc[mi][r];
      v += __shfl_xor(v, 1); v += __shfl_xor(v, 2);
      v += __shfl_xor(v, 4); v += __shfl_xor(v, 8);
      if (lr == 0) sred[w][mi * 16 + lq * 4 + r] = v;   // local row within half
    }
  __syncthreads();

  // ---- epilogue 2: raw scores + p = exp(s - C) ----
  if (tid < 64) {
    const int hh = tid >> 5, loc = tid & 31;
    float s = 0.f;
    #pragma unroll
    for (int j = 0; j < 8; ++j) s += sred[hh * 8 + j][loc];
    score[m0 + tid] = s;                    // raw score (kB normalizes in place)
    ps2[tid] = __expf(s - C);
  }
  __syncthreads();

  // ---- epilogue 3: unnormalized context from L2-warm values rows ----
  const int col = tid & 511, rh = tid >> 9; // 2 threads/col, 32 rows each
  float accc = 0.f;
  #pragma unroll 4
  for (int row = 0; row < 32; ++row)
    accc += ps2[rh * 32 + row] * values[(size_t)(m0 + rh * 32 + row) * D_ + col];
  if (rh == 1) pc[col] = accc;
  __syncthreads();
  if (rh == 0) atomicAdd(&ctxU[(size_t)b * D_ + col], accc + pc[col]);
}

// ---------- kB: normalize (replaces softmax + ctx kernels) ----------
__global__ void kB_final(const float* __restrict__ Vw, float* __restrict__ attn,
                         float* __restrict__ ctx) {
  __shared__ float Cs;
  __shared__ float red[4];
  const int b = blockIdx.x, tid = threadIdx.x;  // 32 blocks x 256
  wave0_sumabs_vw(Vw, &Cs, tid);
  __syncthreads();
  const float C = Cs;
  float* s = attn + b * T_;
  float p[8];
  float sum = 0.f;
  #pragma unroll
  for (int i = 0; i < 8; ++i) { p[i] = __expf(s[tid + i * 256] - C); sum += p[i]; }
  #pragma unroll
  for (int off = 1; off < 64; off <<= 1) sum += __shfl_xor(sum, off);
  if ((tid & 63) == 0) red[tid >> 6] = sum;
  __syncthreads();
  sum = (red[0] + red[1]) + (red[2] + red[3]);
  const float inv = 1.0f / sum;
  #pragma unroll
  for (int i = 0; i < 8; ++i) attn[b * T_ + tid + i * 256] = p[i] * inv;
  #pragma unroll
  for (int i = 0; i < 2; ++i) ctx[b * D_ + tid + i * 256] *= inv;
}

extern "C" void kernel_launch(void* const* d_in, const int* in_sizes, int n_in,
                              void* d_out, int out_size, void* d_ws, size_t ws_size,
                              hipStream_t stream) {
  const float* query = (const float*)d_in[0];
  const float* values = (const float*)d_in[1];
  const float* W1w = (const float*)d_in[2];
  const float* W1b = (const float*)d_in[3];
  const float* W2w = (const float*)d_in[4];
  const float* W2b = (const float*)d_in[5];
  const float* Vw  = (const float*)d_in[6];
  // V_b (d_in[7]) is a constant shift under softmax -> dropped.

  float* out = (float*)d_out;
  float* ctx  = out;                 // [B, D]: unnormalized ctx until kB scales in place
  float* attn = out + B_ * D_;       // [B, T, 1]: raw scores until kB softmaxes in place
  float* score = attn;

  char* ws = (char*)d_ws;            // needs 576 KB (unchanged)
  unsigned* W2P = (unsigned*)ws;                             // 512 KB packed bf16 B
  float* qp    = (float*)(ws + 512 * 1024);                  // 64 KB

  kA_prep<<<320, 256, 0, stream>>>(W2w, W2P, query, W1w, W1b, W2b, qp, ctx);
  k2attn<<<1024, 1024, 0, stream>>>(values, (const unsigned short*)W2P, qp, Vw, score, ctx);
  kB_final<<<32, 256, 0, stream>>>(Vw, attn, ctx);
}

// Round 6
// 262.623 us; speedup vs baseline: 1.0224x; 1.0224x over previous
//
#include <hip/hip_runtime.h>
#include <hip/hip_bf16.h>
#include <cstddef>
#include <cstdint>

#define B_ 32
#define T_ 2048
#define D_ 512
#define U_ 512

typedef __attribute__((ext_vector_type(8))) short bf16x8;   // 8 bf16 = 4 VGPRs
typedef __attribute__((ext_vector_type(4))) float f32x4;    // MFMA 16x16 accum

__device__ __forceinline__ unsigned short f2bf(float f) {
  union { float f; unsigned u; } x; x.f = f;
  unsigned r = x.u + 0x7fffu + ((x.u >> 16) & 1u);  // RNE
  return (unsigned short)(r >> 16);
}
__device__ __forceinline__ float tanh_fast(float x) {
  float e = __expf(2.0f * x);
  return 1.0f - 2.0f * __builtin_amdgcn_rcpf(e + 1.0f);
}

#define AS1C(p) ((const __attribute__((address_space(1))) unsigned*)(p))
#define AS3(p)  ((__attribute__((address_space(3))) unsigned*)(p))

// C = sum |Vw| : tanh-bound => |score| <= C, so exp(s-C) in (0,1] -- softmax needs no
// global max pass. Computed IDENTICALLY (wave-0 only, fixed shfl order) in k2attn and
// kB_final => bit-identical C in both kernels.
__device__ __forceinline__ void wave0_sumabs_vw(const float* __restrict__ Vw,
                                                float* Cs, int tid) {
  if (tid < 64) {
    float c = 0.f;
    #pragma unroll
    for (int i = 0; i < 8; ++i) c += fabsf(Vw[tid + i * 64]);
    c += __shfl_xor(c, 1);  c += __shfl_xor(c, 2);  c += __shfl_xor(c, 4);
    c += __shfl_xor(c, 8);  c += __shfl_xor(c, 16); c += __shfl_xor(c, 32);
    if (tid == 0) *Cs = c;
  }
}

// ---------- kA: W2 pack (blocks 0..63) + q_proj/ctx-zero (64..319) ---------- [R5-verified]
__global__ void kA_prep(const float* __restrict__ W2, unsigned* __restrict__ W2P,
                        const float* __restrict__ query, const float* __restrict__ W1,
                        const float* __restrict__ W1b, const float* __restrict__ W2b,
                        float* __restrict__ qp, float* __restrict__ ctx) {
  const int tid = threadIdx.x;              // 256
  if (blockIdx.x < 64) {
    const int kg = blockIdx.x >> 2, q4 = blockIdx.x & 3;  // 8 k-rows: kg*32+q4*8 ..+7
    __shared__ unsigned short w2s[8][514];
    const float4* W2v = (const float4*)(W2 + (size_t)(kg * 32 + q4 * 8) * U_);
    #pragma unroll
    for (int i = 0; i < 4; ++i) {
      int idx4 = i * 256 + tid;             // float4 index in 8x512 slab (128 per row)
      float4 v = W2v[idx4];
      int r = idx4 >> 7, c = (idx4 & 127) * 4;
      w2s[r][c + 0] = f2bf(v.x); w2s[r][c + 1] = f2bf(v.y);
      w2s[r][c + 2] = f2bf(v.z); w2s[r][c + 3] = f2bf(v.w);
    }
    __syncthreads();
    const int idx = tid & 63;
    const int lr = (idx >> 2) & 15, j = idx & 3;
    const int kb = j * 2;                   // local row within the 8-row slab
    #pragma unroll
    for (int r = 0; r < 8; ++r) {
      int ut = r * 4 + (tid >> 6);
      W2P[ut * 4096 + kg * 256 + q4 * 64 + idx] =
          (unsigned)w2s[kb][ut * 16 + lr] | ((unsigned)w2s[kb + 1][ut * 16 + lr] << 16);
    }
  } else {
    // qproj: 256 blocks = 32 b x 8 u-slices(64). 4-way d-split per u + LDS reduce.
    __shared__ float qs[D_];
    __shared__ float red[4][64];
    const int blk2 = blockIdx.x - 64;       // 0..255
    const int b = blk2 >> 3, us = blk2 & 7;
    const int ul = tid & 63, dq = tid >> 6; // u-local, d-quarter
    const int u = us * 64 + ul;
    qs[tid] = query[b * D_ + tid];
    qs[tid + 256] = query[b * D_ + tid + 256];
    __syncthreads();
    float a0 = 0, a1 = 0, a2 = 0, a3 = 0;
    const int d0 = dq * 128;
    for (int d = 0; d < 128; d += 4) {
      a0 += qs[d0 + d + 0] * W1[(size_t)(d0 + d + 0) * U_ + u];
      a1 += qs[d0 + d + 1] * W1[(size_t)(d0 + d + 1) * U_ + u];
      a2 += qs[d0 + d + 2] * W1[(size_t)(d0 + d + 2) * U_ + u];
      a3 += qs[d0 + d + 3] * W1[(size_t)(d0 + d + 3) * U_ + u];
    }
    red[dq][ul] = (a0 + a1) + (a2 + a3);
    __syncthreads();
    if (dq == 0) {
      float s = red[0][ul] + red[1][ul] + red[2][ul] + red[3][ul];
      qp[b * U_ + u] = s + W1b[u] + W2b[u];
    }
    if (tid < 64) ctx[blk2 * 64 + tid] = 0.0f;  // 256*64 = 16384: zero unnormalized ctx
  }
}

// ---------- k2attn v7: FENCE-FREE. R0's proven loop discipline + fused epilogue ----------
// Theory (R0=83.5us fence-free vs R3/R4/R5=107/97/111 fenced): sched_barrier(0)+asm-waitcnt
// pinning defeats hipcc's own fine-grained scheduling (guide m141: 874->510 regression).
// v7 removes ALL fences/asm/setprio and restores R0's exact structure:
//   * A: fp32 eighths via global_load_lds DMA, double-buffered 2x8KB LDS, R0-verified
//     XOR swizzle (0 conflicts): stage pos c holds chunk c^(row&15); read p0=(kq*8+lq*2)^lr.
//   * one __syncthreads per K-eighth (compiler emits its own vmcnt/lgkmcnt elsewhere).
//   * B: Bc/Bn source-level double-buffer, loaded 1 kq-step ahead (R0 pattern).
// New vs R0: M=32 x FULL U block (512 thr, 8 waves, acc 32/thread -> ~90 total regs ->
// 4 waves/SIMD -> 2 blocks = 16 waves/CU, 2x R0's TLP) + fused epilogue (R3-verified):
// tanh+Vw reduce -> raw score + p=exp(s-C) -> unnormalized ctx from L2-warm values.
__global__ __launch_bounds__(512, 4) void k2attn(
    const float* __restrict__ values, const unsigned short* __restrict__ W2P,
    const float* __restrict__ qp, const float* __restrict__ Vw,
    float* __restrict__ score, float* __restrict__ ctxU) {
  __shared__ __align__(16) float av[2][2048];   // 2 x 8 KB fp32 A buffers (32 rows x 64 f)
  __shared__ float sred[8][32];
  __shared__ float ps2[32];
  __shared__ float Cs;

  const int tid = threadIdx.x;              // 512
  const int bx = blockIdx.x;                // 2048 = 64 chunks x 32 batches
  const int m0 = bx * 32;                   // flat row (b*2048 + t); never crosses batch
  const int b = m0 >> 11;
  const int l = tid & 63, w = tid >> 6;     // 8 waves; wave w owns u-tiles w*4..w*4+3
  const int lr = l & 15, lq = l >> 4;

  // staging: thread t covers row t>>4 (0..31), source chunk (t&15)^(row&15) -> linear LDS
  const int row_st = tid >> 4;
  const int qsw = (tid & 15) ^ (row_st & 15);
  const float* vsrc = values + (size_t)(m0 + row_st) * D_ + qsw * 4;

  f32x4 acc[2][4];
  #pragma unroll
  for (int mi = 0; mi < 2; ++mi)
    #pragma unroll
    for (int ni = 0; ni < 4; ++ni) acc[mi][ni] = (f32x4){0.f, 0.f, 0.f, 0.f};

  const unsigned short* Bb = W2P + (size_t)(w * 4) * 8192 + (size_t)l * 8;

  auto stage = [&](int e, int p) {          // DMA eighth e into buffer p (1 instr/thread)
    __builtin_amdgcn_global_load_lds(AS1C(vsrc + e * 64), AS3(&av[p][w * 256]), 16, 0, 0);
  };

  wave0_sumabs_vw(Vw, &Cs, tid);

  bf16x8 Bc[4], Bn[4];
  stage(0, 0);
  #pragma unroll
  for (int ni = 0; ni < 4; ++ni) Bc[ni] = *(const bf16x8*)(Bb + (size_t)ni * 8192);

  for (int kg = 0; kg < 16; ++kg) {         // K = 512 = 16 x K32
    const int e = kg >> 1, p = e & 1;
    if ((kg & 1) == 0) {
      __syncthreads();                      // drains DMA(e) (a full eighth in flight)
      if (e < 7) stage(e + 1, p ^ 1);       // overlaps compute of kg, kg+1
    }
    if (kg < 15) {
      #pragma unroll
      for (int ni = 0; ni < 4; ++ni)
        Bn[ni] = *(const bf16x8*)(Bb + (size_t)ni * 8192 + (size_t)(kg + 1) * 512);
    }
    const int kq = kg & 1;
    const int p0 = (kq * 8 + lq * 2) ^ lr;  // swizzled position of chunk pair
    bf16x8 a[2];
    #pragma unroll
    for (int mi = 0; mi < 2; ++mi) {
      const int row = mi * 16 + lr;
      f32x4 flo = *(const f32x4*)&av[p][row * 64 + (p0 << 2)];
      f32x4 fhi = *(const f32x4*)&av[p][row * 64 + ((p0 ^ 1) << 2)];
      union { bf16x8 v; __hip_bfloat162 h[4]; } A;
      A.h[0] = __float22bfloat162_rn(make_float2(flo.x, flo.y));
      A.h[1] = __float22bfloat162_rn(make_float2(flo.z, flo.w));
      A.h[2] = __float22bfloat162_rn(make_float2(fhi.x, fhi.y));
      A.h[3] = __float22bfloat162_rn(make_float2(fhi.z, fhi.w));
      a[mi] = A.v;
    }
    #pragma unroll
    for (int ni = 0; ni < 4; ++ni)
      #pragma unroll
      for (int mi = 0; mi < 2; ++mi)
        acc[mi][ni] = __builtin_amdgcn_mfma_f32_16x16x32_bf16(a[mi], Bc[ni], acc[mi][ni], 0, 0, 0);
    #pragma unroll
    for (int ni = 0; ni < 4; ++ni) Bc[ni] = Bn[ni];
  }

  // ---- epilogue 1: tanh + Vw-weighted reduce over u (C/D: col=lr -> u, row=lq*4+r) ----
  float sacc[2][4];
  #pragma unroll
  for (int mi = 0; mi < 2; ++mi)
    #pragma unroll
    for (int r = 0; r < 4; ++r) sacc[mi][r] = 0.0f;
  #pragma unroll
  for (int ni = 0; ni < 4; ++ni) {
    int u = (w * 4 + ni) * 16 + lr;
    float qpv = qp[b * U_ + u], vv = Vw[u];
    #pragma unroll
    for (int mi = 0; mi < 2; ++mi)
      #pragma unroll
      for (int r = 0; r < 4; ++r)
        sacc[mi][r] += tanh_fast(acc[mi][ni][r] + qpv) * vv;
  }
  #pragma unroll
  for (int mi = 0; mi < 2; ++mi)
    #pragma unroll
    for (int r = 0; r < 4; ++r) {
      float v = sacc[mi][r];
      v += __shfl_xor(v, 1); v += __shfl_xor(v, 2);
      v += __shfl_xor(v, 4); v += __shfl_xor(v, 8);
      if (lr == 0) sred[w][mi * 16 + lq * 4 + r] = v;
    }
  __syncthreads();

  // ---- epilogue 2: raw scores + p = exp(s - C) ----
  if (tid < 32) {
    float s = 0.f;
    #pragma unroll
    for (int wv = 0; wv < 8; ++wv) s += sred[wv][tid];
    score[m0 + tid] = s;                    // raw score (kB normalizes in place)
    ps2[tid] = __expf(s - Cs);
  }
  __syncthreads();

  // ---- epilogue 3: unnormalized context from L2-warm values rows ----
  float accc = 0.f;
  const int col = tid;                      // 512 threads <-> 512 cols
  #pragma unroll 4
  for (int row = 0; row < 32; ++row)
    accc += ps2[row] * values[(size_t)(m0 + row) * D_ + col];
  atomicAdd(&ctxU[(size_t)b * D_ + col], accc);
}

// ---------- kB: normalize (replaces softmax + ctx kernels) ---------- [R3-verified]
__global__ void kB_final(const float* __restrict__ Vw, float* __restrict__ attn,
                         float* __restrict__ ctx) {
  __shared__ float Cs;
  __shared__ float red[4];
  const int b = blockIdx.x, tid = threadIdx.x;  // 32 blocks x 256
  wave0_sumabs_vw(Vw, &Cs, tid);
  __syncthreads();
  const float C = Cs;
  float* s = attn + b * T_;
  float p[8];
  float sum = 0.f;
  #pragma unroll
  for (int i = 0; i < 8; ++i) { p[i] = __expf(s[tid + i * 256] - C); sum += p[i]; }
  #pragma unroll
  for (int off = 1; off < 64; off <<= 1) sum += __shfl_xor(sum, off);
  if ((tid & 63) == 0) red[tid >> 6] = sum;
  __syncthreads();
  sum = (red[0] + red[1]) + (red[2] + red[3]);
  const float inv = 1.0f / sum;
  #pragma unroll
  for (int i = 0; i < 8; ++i) attn[b * T_ + tid + i * 256] = p[i] * inv;
  #pragma unroll
  for (int i = 0; i < 2; ++i) ctx[b * D_ + tid + i * 256] *= inv;
}

extern "C" void kernel_launch(void* const* d_in, const int* in_sizes, int n_in,
                              void* d_out, int out_size, void* d_ws, size_t ws_size,
                              hipStream_t stream) {
  const float* query = (const float*)d_in[0];
  const float* values = (const float*)d_in[1];
  const float* W1w = (const float*)d_in[2];
  const float* W1b = (const float*)d_in[3];
  const float* W2w = (const float*)d_in[4];
  const float* W2b = (const float*)d_in[5];
  const float* Vw  = (const float*)d_in[6];
  // V_b (d_in[7]) is a constant shift under softmax -> dropped.

  float* out = (float*)d_out;
  float* ctx  = out;                 // [B, D]: unnormalized ctx until kB scales in place
  float* attn = out + B_ * D_;       // [B, T, 1]: raw scores until kB softmaxes in place
  float* score = attn;

  char* ws = (char*)d_ws;            // needs 576 KB (unchanged)
  unsigned* W2P = (unsigned*)ws;                             // 512 KB packed bf16 B
  float* qp    = (float*)(ws + 512 * 1024);                  // 64 KB

  kA_prep<<<320, 256, 0, stream>>>(W2w, W2P, query, W1w, W1b, W2b, qp, ctx);
  k2attn<<<2048, 512, 0, stream>>>(values, (const unsigned short*)W2P, qp, Vw, score, ctx);
  kB_final<<<32, 256, 0, stream>>>(Vw, attn, ctx);
}

// Round 7
// 241.610 us; speedup vs baseline: 1.1113x; 1.0870x over previous
//
#include <hip/hip_runtime.h>
#include <hip/hip_bf16.h>
#include <cstddef>
#include <cstdint>

#define B_ 32
#define T_ 2048
#define D_ 512
#define U_ 512

typedef __attribute__((ext_vector_type(8))) short bf16x8;   // 8 bf16 = 4 VGPRs
typedef __attribute__((ext_vector_type(4))) float f32x4;    // MFMA 16x16 accum

__device__ __forceinline__ unsigned short f2bf(float f) {
  union { float f; unsigned u; } x; x.f = f;
  unsigned r = x.u + 0x7fffu + ((x.u >> 16) & 1u);  // RNE
  return (unsigned short)(r >> 16);
}
__device__ __forceinline__ float tanh_fast(float x) {
  float e = __expf(2.0f * x);
  return 1.0f - 2.0f * __builtin_amdgcn_rcpf(e + 1.0f);
}

#define AS1C(p) ((const __attribute__((address_space(1))) unsigned*)(p))
#define AS3(p)  ((__attribute__((address_space(3))) unsigned*)(p))

// C = sum |Vw| : tanh-bound => |score| <= C, so exp(s-C) in (0,1] -- softmax needs no
// global max pass. Computed IDENTICALLY (wave-0 only, fixed shfl order) in k2attn and
// kB_final => bit-identical C in both kernels.
__device__ __forceinline__ void wave0_sumabs_vw(const float* __restrict__ Vw,
                                                float* Cs, int tid) {
  if (tid < 64) {
    float c = 0.f;
    #pragma unroll
    for (int i = 0; i < 8; ++i) c += fabsf(Vw[tid + i * 64]);
    c += __shfl_xor(c, 1);  c += __shfl_xor(c, 2);  c += __shfl_xor(c, 4);
    c += __shfl_xor(c, 8);  c += __shfl_xor(c, 16); c += __shfl_xor(c, 32);
    if (tid == 0) *Cs = c;
  }
}

// ---------- kA: W2 pack (blocks 0..63) + q_proj/ctx-zero (64..319) ---------- [R5-verified]
__global__ void kA_prep(const float* __restrict__ W2, unsigned* __restrict__ W2P,
                        const float* __restrict__ query, const float* __restrict__ W1,
                        const float* __restrict__ W1b, const float* __restrict__ W2b,
                        float* __restrict__ qp, float* __restrict__ ctx) {
  const int tid = threadIdx.x;              // 256
  if (blockIdx.x < 64) {
    const int kg = blockIdx.x >> 2, q4 = blockIdx.x & 3;  // 8 k-rows: kg*32+q4*8 ..+7
    __shared__ unsigned short w2s[8][514];
    const float4* W2v = (const float4*)(W2 + (size_t)(kg * 32 + q4 * 8) * U_);
    #pragma unroll
    for (int i = 0; i < 4; ++i) {
      int idx4 = i * 256 + tid;             // float4 index in 8x512 slab (128 per row)
      float4 v = W2v[idx4];
      int r = idx4 >> 7, c = (idx4 & 127) * 4;
      w2s[r][c + 0] = f2bf(v.x); w2s[r][c + 1] = f2bf(v.y);
      w2s[r][c + 2] = f2bf(v.z); w2s[r][c + 3] = f2bf(v.w);
    }
    __syncthreads();
    const int idx = tid & 63;
    const int lr = (idx >> 2) & 15, j = idx & 3;
    const int kb = j * 2;                   // local row within the 8-row slab
    #pragma unroll
    for (int r = 0; r < 8; ++r) {
      int ut = r * 4 + (tid >> 6);
      W2P[ut * 4096 + kg * 256 + q4 * 64 + idx] =
          (unsigned)w2s[kb][ut * 16 + lr] | ((unsigned)w2s[kb + 1][ut * 16 + lr] << 16);
    }
  } else {
    // qproj: 256 blocks = 32 b x 8 u-slices(64). 4-way d-split per u + LDS reduce.
    __shared__ float qs[D_];
    __shared__ float red[4][64];
    const int blk2 = blockIdx.x - 64;       // 0..255
    const int b = blk2 >> 3, us = blk2 & 7;
    const int ul = tid & 63, dq = tid >> 6; // u-local, d-quarter
    const int u = us * 64 + ul;
    qs[tid] = query[b * D_ + tid];
    qs[tid + 256] = query[b * D_ + tid + 256];
    __syncthreads();
    float a0 = 0, a1 = 0, a2 = 0, a3 = 0;
    const int d0 = dq * 128;
    for (int d = 0; d < 128; d += 4) {
      a0 += qs[d0 + d + 0] * W1[(size_t)(d0 + d + 0) * U_ + u];
      a1 += qs[d0 + d + 1] * W1[(size_t)(d0 + d + 1) * U_ + u];
      a2 += qs[d0 + d + 2] * W1[(size_t)(d0 + d + 2) * U_ + u];
      a3 += qs[d0 + d + 3] * W1[(size_t)(d0 + d + 3) * U_ + u];
    }
    red[dq][ul] = (a0 + a1) + (a2 + a3);
    __syncthreads();
    if (dq == 0) {
      float s = red[0][ul] + red[1][ul] + red[2][ul] + red[3][ul];
      qp[b * U_ + u] = s + W1b[u] + W2b[u];
    }
    if (tid < 64) ctx[blk2 * 64 + tid] = 0.0f;  // 256*64 = 16384: zero unnormalized ctx
  }
}

// ---------- k2attn v8: R0's proven wave geometry (4x4 acc) + fused epilogue ----------
// Evidence across R0..R6: R0 (64m, 4x4 acc/wave, 16 MFMA per B-quad, DMA dbuf, plain
// __syncthreads, Bc/Bn 1-step) = 83.5us; every deviation (smaller acc tile, fences,
// counted vmcnt, deeper rings) = 97-111us. v8 keeps R0's per-wave K-loop VERBATIM and
// changes only the block shape: 64m x FULL U (512 thr, 8 waves, wave w owns u-group w*4
// ..w*4+3) so the block owns all its scores -> R3-verified fused epilogue (score +
// exp(s-C) + unnormalized ctx), eliminating the separate softmax/ctx kernels.
// Grid 1024. B traffic: 512KB/block over 64 rows = R0's per-row cost (512MB total).
// A: fp32 eighths via global_load_lds DMA (2 instr/thread: rows r, r+32), double-buffered
// 2x16KB, R0-verified XOR swizzle (0 conflicts): pos c holds chunk c^(row&15), read
// p0=(kq*8+lq*2)^lr. One __syncthreads per eighth; NO fences/asm/setprio (m141 lesson).
__global__ __launch_bounds__(512, 4) void k2attn(
    const float* __restrict__ values, const unsigned short* __restrict__ W2P,
    const float* __restrict__ qp, const float* __restrict__ Vw,
    float* __restrict__ score, float* __restrict__ ctxU) {
  __shared__ __align__(16) float av[2][4096];   // 2 x 16 KB fp32 A buffers (64 rows x 64 f)
  __shared__ float sred[8][64];
  __shared__ float ps2[64];
  __shared__ float Cs;

  const int tid = threadIdx.x;              // 512
  const int bx = blockIdx.x;                // 1024 = 32 chunks x 32 batches
  const int m0 = bx * 64;                   // flat row (b*2048 + t); never crosses batch
  const int b = m0 >> 11;
  const int l = tid & 63, w = tid >> 6;     // 8 waves; wave w owns u-tiles w*4..w*4+3
  const int lr = l & 15, lq = l >> 4;

  // staging: thread t covers rows r0=t>>4 and r0+32; source chunk (t&15)^(row&15)
  const int r0 = tid >> 4;
  const int c0 = tid & 15;
  const float* vsrc0 = values + (size_t)(m0 + r0) * D_ + (c0 ^ (r0 & 15)) * 4;
  const float* vsrc1 = values + (size_t)(m0 + 32 + r0) * D_ + (c0 ^ (r0 & 15)) * 4;

  f32x4 acc[4][4];                          // R0's 4x4 fragment tile (64 acc regs)
  #pragma unroll
  for (int mi = 0; mi < 4; ++mi)
    #pragma unroll
    for (int ni = 0; ni < 4; ++ni) acc[mi][ni] = (f32x4){0.f, 0.f, 0.f, 0.f};

  const unsigned short* Bb = W2P + (size_t)(w * 4) * 8192 + (size_t)l * 8;

  auto stage = [&](int e, int p) {          // DMA eighth e into buffer p (2 instr/thread)
    __builtin_amdgcn_global_load_lds(AS1C(vsrc0 + e * 64), AS3(&av[p][(r0) * 64 + ((tid & 15) << 2)]), 16, 0, 0);
    __builtin_amdgcn_global_load_lds(AS1C(vsrc1 + e * 64), AS3(&av[p][(32 + r0) * 64 + ((tid & 15) << 2)]), 16, 0, 0);
  };

  wave0_sumabs_vw(Vw, &Cs, tid);

  bf16x8 Bc[4], Bn[4];
  stage(0, 0);
  #pragma unroll
  for (int ni = 0; ni < 4; ++ni) Bc[ni] = *(const bf16x8*)(Bb + (size_t)ni * 8192);

  for (int kg = 0; kg < 16; ++kg) {         // K = 512 = 16 x K32
    const int e = kg >> 1, p = e & 1;
    if ((kg & 1) == 0) {
      __syncthreads();                      // drains DMA(e) (a full eighth in flight)
      if (e < 7) stage(e + 1, p ^ 1);       // overlaps compute of kg, kg+1
    }
    if (kg < 15) {
      #pragma unroll
      for (int ni = 0; ni < 4; ++ni)
        Bn[ni] = *(const bf16x8*)(Bb + (size_t)ni * 8192 + (size_t)(kg + 1) * 512);
    }
    const int kq = kg & 1;
    const int p0 = (kq * 8 + lq * 2) ^ lr;  // swizzled position of chunk pair
    bf16x8 a[4];
    #pragma unroll
    for (int mi = 0; mi < 4; ++mi) {
      const int row = mi * 16 + lr;
      f32x4 flo = *(const f32x4*)&av[p][row * 64 + (p0 << 2)];
      f32x4 fhi = *(const f32x4*)&av[p][row * 64 + ((p0 ^ 1) << 2)];
      union { bf16x8 v; __hip_bfloat162 h[4]; } A;
      A.h[0] = __float22bfloat162_rn(make_float2(flo.x, flo.y));
      A.h[1] = __float22bfloat162_rn(make_float2(flo.z, flo.w));
      A.h[2] = __float22bfloat162_rn(make_float2(fhi.x, fhi.y));
      A.h[3] = __float22bfloat162_rn(make_float2(fhi.z, fhi.w));
      a[mi] = A.v;
    }
    #pragma unroll
    for (int ni = 0; ni < 4; ++ni)
      #pragma unroll
      for (int mi = 0; mi < 4; ++mi)
        acc[mi][ni] = __builtin_amdgcn_mfma_f32_16x16x32_bf16(a[mi], Bc[ni], acc[mi][ni], 0, 0, 0);
    #pragma unroll
    for (int ni = 0; ni < 4; ++ni) Bc[ni] = Bn[ni];
  }

  // ---- epilogue 1: tanh + Vw-weighted reduce over u (C/D: col=lr -> u, row=lq*4+r) ----
  float sacc[4][4];
  #pragma unroll
  for (int mi = 0; mi < 4; ++mi)
    #pragma unroll
    for (int r = 0; r < 4; ++r) sacc[mi][r] = 0.0f;
  #pragma unroll
  for (int ni = 0; ni < 4; ++ni) {
    int u = (w * 4 + ni) * 16 + lr;
    float qpv = qp[b * U_ + u], vv = Vw[u];
    #pragma unroll
    for (int mi = 0; mi < 4; ++mi)
      #pragma unroll
      for (int r = 0; r < 4; ++r)
        sacc[mi][r] += tanh_fast(acc[mi][ni][r] + qpv) * vv;
  }
  #pragma unroll
  for (int mi = 0; mi < 4; ++mi)
    #pragma unroll
    for (int r = 0; r < 4; ++r) {
      float v = sacc[mi][r];
      v += __shfl_xor(v, 1); v += __shfl_xor(v, 2);
      v += __shfl_xor(v, 4); v += __shfl_xor(v, 8);
      if (lr == 0) sred[w][mi * 16 + lq * 4 + r] = v;
    }
  __syncthreads();

  // ---- epilogue 2: raw scores + p = exp(s - C) ----
  if (tid < 64) {
    float s = 0.f;
    #pragma unroll
    for (int wv = 0; wv < 8; ++wv) s += sred[wv][tid];
    score[m0 + tid] = s;                    // raw score (kB normalizes in place)
    ps2[tid] = __expf(s - Cs);
  }
  __syncthreads();

  // ---- epilogue 3: unnormalized context from L2-warm values rows ----
  float accc = 0.f;
  const int col = tid;                      // 512 threads <-> 512 cols
  #pragma unroll 4
  for (int row = 0; row < 64; ++row)
    accc += ps2[row] * values[(size_t)(m0 + row) * D_ + col];
  atomicAdd(&ctxU[(size_t)b * D_ + col], accc);
}

// ---------- kB: normalize (replaces softmax + ctx kernels) ---------- [R3-verified]
__global__ void kB_final(const float* __restrict__ Vw, float* __restrict__ attn,
                         float* __restrict__ ctx) {
  __shared__ float Cs;
  __shared__ float red[4];
  const int b = blockIdx.x, tid = threadIdx.x;  // 32 blocks x 256
  wave0_sumabs_vw(Vw, &Cs, tid);
  __syncthreads();
  const float C = Cs;
  float* s = attn + b * T_;
  float p[8];
  float sum = 0.f;
  #pragma unroll
  for (int i = 0; i < 8; ++i) { p[i] = __expf(s[tid + i * 256] - C); sum += p[i]; }
  #pragma unroll
  for (int off = 1; off < 64; off <<= 1) sum += __shfl_xor(sum, off);
  if ((tid & 63) == 0) red[tid >> 6] = sum;
  __syncthreads();
  sum = (red[0] + red[1]) + (red[2] + red[3]);
  const float inv = 1.0f / sum;
  #pragma unroll
  for (int i = 0; i < 8; ++i) attn[b * T_ + tid + i * 256] = p[i] * inv;
  #pragma unroll
  for (int i = 0; i < 2; ++i) ctx[b * D_ + tid + i * 256] *= inv;
}

extern "C" void kernel_launch(void* const* d_in, const int* in_sizes, int n_in,
                              void* d_out, int out_size, void* d_ws, size_t ws_size,
                              hipStream_t stream) {
  const float* query = (const float*)d_in[0];
  const float* values = (const float*)d_in[1];
  const float* W1w = (const float*)d_in[2];
  const float* W1b = (const float*)d_in[3];
  const float* W2w = (const float*)d_in[4];
  const float* W2b = (const float*)d_in[5];
  const float* Vw  = (const float*)d_in[6];
  // V_b (d_in[7]) is a constant shift under softmax -> dropped.

  float* out = (float*)d_out;
  float* ctx  = out;                 // [B, D]: unnormalized ctx until kB scales in place
  float* attn = out + B_ * D_;       // [B, T, 1]: raw scores until kB softmaxes in place
  float* score = attn;

  char* ws = (char*)d_ws;            // needs 576 KB (unchanged)
  unsigned* W2P = (unsigned*)ws;                             // 512 KB packed bf16 B
  float* qp    = (float*)(ws + 512 * 1024);                  // 64 KB

  kA_prep<<<320, 256, 0, stream>>>(W2w, W2P, query, W1w, W1b, W2b, qp, ctx);
  k2attn<<<1024, 512, 0, stream>>>(values, (const unsigned short*)W2P, qp, Vw, score, ctx);
  kB_final<<<32, 256, 0, stream>>>(Vw, attn, ctx);
}